// Round 1
// baseline (535.672 us; speedup 1.0000x reference)
//
#include <hip/hip_runtime.h>
#include <math.h>

// Problem constants (from reference setup_inputs)
#define BB 32
#define TT 750
#define DD 2048
#define CC 20
#define MM 750
#define SS 64
#define NTILE 12     // ceil(750/64)
#define MTILE 64
#define DCH 64       // D-chunk staged in LDS
#define ROWP 68      // padded LDS row stride (floats): 64 + 4 (16B-aligned rows)

#define ALPHA_W 0.0005f
#define BETA_W 0.1f
#define MARGIN_W 100.0f
#define GCN_W 0.1f
#define EPS_V 1e-8f

// ---------------------------------------------------------------------------
// Kernel 1: BCE losses (loss_cls, loss_be). One block, 640 threads (B*C).
// ---------------------------------------------------------------------------
__global__ __launch_bounds__(640) void bce_kernel(
    const float* __restrict__ score_act, const float* __restrict__ score_bkg,
    const float* __restrict__ label, float* __restrict__ loss01) {
  int tid = threadIdx.x;            // 0..639
  int b = tid / CC;
  int c = tid % CC;

  float rs = 0.f;
  for (int k = 0; k < CC; ++k) rs += label[b * CC + k];
  float ln = label[b * CC + c] / rs;

  float pa = score_act[tid];
  float v_cls = ln * logf(pa) + (1.f - ln) * logf(1.f - pa);
  float pb = score_bkg[tid];
  const float tb = 1.f / (float)CC;
  float v_be = tb * logf(pb) + (1.f - tb) * logf(1.f - pb);

  // reduce over 640 threads = 10 waves
  for (int off = 32; off; off >>= 1) {
    v_cls += __shfl_down(v_cls, off, 64);
    v_be  += __shfl_down(v_be, off, 64);
  }
  __shared__ float rc[10], rb[10];
  int wave = tid >> 6;
  if ((tid & 63) == 0) { rc[wave] = v_cls; rb[wave] = v_be; }
  __syncthreads();
  if (tid == 0) {
    float sc = 0.f, sb = 0.f;
    for (int w = 0; w < 10; ++w) { sc += rc[w]; sb += rb[w]; }
    loss01[0] = -sc / (float)(BB * CC);
    loss01[1] = -sb / (float)(BB * CC);
  }
}

// ---------------------------------------------------------------------------
// Kernel 2: per-batch ||mean_t feat||^2 partials. grid (8, B), 256 threads.
// partials[b*8 + blk] = sum over this block's 256 d's of mean^2
// ---------------------------------------------------------------------------
__global__ __launch_bounds__(256) void feat_norm_kernel(
    const float* __restrict__ feat, float* __restrict__ partials) {
  int blk = blockIdx.x;     // 0..7
  int b = blockIdx.y;
  int d = blk * 256 + threadIdx.x;
  const float* p = feat + (size_t)b * TT * DD + d;
  float s = 0.f;
  for (int t = 0; t < TT; ++t) s += p[(size_t)t * DD];
  float mean = s / (float)TT;
  float v = mean * mean;
  for (int off = 32; off; off >>= 1) v += __shfl_down(v, off, 64);
  __shared__ float red[4];
  if ((threadIdx.x & 63) == 0) red[threadIdx.x >> 6] = v;
  __syncthreads();
  if (threadIdx.x == 0)
    partials[b * 8 + blk] = red[0] + red[1] + red[2] + red[3];
}

// ---------------------------------------------------------------------------
// Kernel 3: GCN tile kernel. grid (NTILE, B), 256 threads.
// Each block: batch b, m-tile of 64. Computes cross[s=0..63][m in tile],
// n2 for tile m's, s2 for sampled nodes, then per-(s) masked argmax/argmin
// over the tile's m with JAX tie-breaking (first/lowest index wins).
// Emits per-(b,s,tile) candidates: {pos_d2, pos_idx, pos_cross, pos_n2,
//                                   neg_d2, neg_idx, neg_cross, neg_n2}.
// ---------------------------------------------------------------------------
__global__ __launch_bounds__(256) void gcn_tile_kernel(
    const float* __restrict__ nodes, const int* __restrict__ nlab,
    const int* __restrict__ sidx, float* __restrict__ cand,
    float* __restrict__ s2out) {
  int tile = blockIdx.x;
  int b = blockIdx.y;
  int tid = threadIdx.x;

  __shared__ float sA[SS * ROWP];   // s_nodes chunk [s][d]
  __shared__ float sB[MTILE * ROWP];// nodes tile chunk [ml][d]
  __shared__ float sS2[SS];
  __shared__ float sN2[MTILE];
  __shared__ int sSlab[SS];
  __shared__ int sMlab[MTILE];

  // stage labels
  if (tid < SS) {
    int si = sidx[b * SS + tid];
    sSlab[tid] = nlab[b * MM + si];
  } else if (tid >= 64 && tid < 128) {
    int ml = tid - 64;
    int m = tile * MTILE + ml;
    sMlab[ml] = (m < MM) ? nlab[b * MM + m] : -2;  // -2: invalid (OOB)
  }

  // staging pointers: thread loads rows r = (tid>>4) + 16k, 16B col (tid&15)*4
  int r0 = tid >> 4;   // 0..15 (also = s-group for compute)
  int d4 = tid & 15;
  const float* aptr[4];
  const float* bptr[4];
  bool bvalid[4];
  for (int k = 0; k < 4; ++k) {
    int s = r0 + 16 * k;
    int si = sidx[b * SS + s];
    aptr[k] = nodes + ((size_t)b * MM + si) * DD + d4 * 4;
    int m = tile * MTILE + r0 + 16 * k;
    bvalid[k] = (m < MM);
    bptr[k] = nodes + ((size_t)b * MM + (bvalid[k] ? m : 0)) * DD + d4 * 4;
  }

  float aSq[4] = {0.f, 0.f, 0.f, 0.f};
  float bSq[4] = {0.f, 0.f, 0.f, 0.f};
  int mq = tid & 15;       // m-group
  int sBase = r0 * 4;      // this thread's 4 s rows
  int mBase = mq * 4;      // this thread's 4 m rows
  float acc[4][4];
#pragma unroll
  for (int i = 0; i < 4; ++i)
#pragma unroll
    for (int j = 0; j < 4; ++j) acc[i][j] = 0.f;

  for (int ch = 0; ch < DD / DCH; ++ch) {
    int d0 = ch * DCH;
    __syncthreads();  // protect previous-iteration LDS reads
#pragma unroll
    for (int k = 0; k < 4; ++k) {
      float4 v = *(const float4*)(aptr[k] + d0);
      *(float4*)&sA[(r0 + 16 * k) * ROWP + d4 * 4] = v;
      aSq[k] += v.x * v.x + v.y * v.y + v.z * v.z + v.w * v.w;
      float4 w = bvalid[k] ? *(const float4*)(bptr[k] + d0)
                           : make_float4(0.f, 0.f, 0.f, 0.f);
      *(float4*)&sB[(r0 + 16 * k) * ROWP + d4 * 4] = w;
      bSq[k] += w.x * w.x + w.y * w.y + w.z * w.z + w.w * w.w;
    }
    __syncthreads();
#pragma unroll
    for (int d = 0; d < DCH; d += 4) {
      float4 a[4], bb[4];
#pragma unroll
      for (int i = 0; i < 4; ++i)
        a[i] = *(const float4*)&sA[(sBase + i) * ROWP + d];
#pragma unroll
      for (int j = 0; j < 4; ++j)
        bb[j] = *(const float4*)&sB[(mBase + j) * ROWP + d];
#pragma unroll
      for (int i = 0; i < 4; ++i)
#pragma unroll
        for (int j = 0; j < 4; ++j)
          acc[i][j] += a[i].x * bb[j].x + a[i].y * bb[j].y +
                       a[i].z * bb[j].z + a[i].w * bb[j].w;
    }
  }

  // reduce row sums of squares across the 16 loader lanes (consecutive tids)
#pragma unroll
  for (int k = 0; k < 4; ++k) {
    float va = aSq[k], vb = bSq[k];
    for (int off = 8; off; off >>= 1) {
      va += __shfl_down(va, off, 16);
      vb += __shfl_down(vb, off, 16);
    }
    if (mq == 0) { sS2[r0 + 16 * k] = va; sN2[r0 + 16 * k] = vb; }
  }
  __syncthreads();

  if (tile == 0 && tid < SS) s2out[b * SS + tid] = sS2[tid];

  // per-s selection over this thread's 4 m's, then over the 16 mq lanes
#pragma unroll
  for (int i = 0; i < 4; ++i) {
    int s = sBase + i;
    int slab = sSlab[s];
    float s2 = sS2[s];

    float posD = -3.4e38f, posC = 0.f, posN = 0.f;
    int posI = -1;
    float negD = 3.4e38f, negC = 0.f, negN = 0.f;
    int negI = -1;
#pragma unroll
    for (int j = 0; j < 4; ++j) {
      int ml = mBase + j;
      int m = tile * MTILE + ml;
      int lab = sMlab[ml];
      float cva = acc[i][j];
      float n2 = sN2[ml];
      float d2 = fmaxf(s2 + n2 - 2.f * cva, 0.f);
      bool valid = (lab >= 0);
      bool same = valid && (lab == slab);
      bool opp = valid && (lab != slab);
      if (same && (posI < 0 || d2 > posD)) { posD = d2; posI = m; posC = cva; posN = n2; }
      if (opp && (negI < 0 || d2 < negD)) { negD = d2; negI = m; negC = cva; negN = n2; }
    }
    // tuple reduce across mq lanes (width 16); lower lane = lower m.
    for (int off = 8; off; off >>= 1) {
      float oD = __shfl_down(posD, off, 16);
      int oI = __shfl_down(posI, off, 16);
      float oC = __shfl_down(posC, off, 16);
      float oN = __shfl_down(posN, off, 16);
      bool take = (oI >= 0) && (posI < 0 || oD > posD || (oD == posD && oI < posI));
      if (take) { posD = oD; posI = oI; posC = oC; posN = oN; }
      oD = __shfl_down(negD, off, 16);
      oI = __shfl_down(negI, off, 16);
      oC = __shfl_down(negC, off, 16);
      oN = __shfl_down(negN, off, 16);
      take = (oI >= 0) && (negI < 0 || oD < negD || (oD == negD && oI < negI));
      if (take) { negD = oD; negI = oI; negC = oC; negN = oN; }
    }
    if (mq == 0) {
      size_t base = (((size_t)b * SS + s) * NTILE + tile) * 8;
      *(float4*)&cand[base] =
          make_float4(posD, __int_as_float(posI), posC, posN);
      *(float4*)&cand[base + 4] =
          make_float4(negD, __int_as_float(negI), negC, negN);
    }
  }
}

// ---------------------------------------------------------------------------
// Kernel 4: combine tiles per (b,s), compute cosine losses, per-b sum.
// grid (B), 64 threads.
// ---------------------------------------------------------------------------
__global__ __launch_bounds__(64) void gcn_combine_kernel(
    const float* __restrict__ cand, const float* __restrict__ s2arr,
    float* __restrict__ gcn_b) {
  int b = blockIdx.x;
  int s = threadIdx.x;
  const float* cb = cand + ((size_t)b * SS + s) * NTILE * 8;

  float posD = -3.4e38f, posC = 0.f, posN = 0.f;
  int posI = -1;
  float negD = 3.4e38f, negC = 0.f, negN = 0.f;
  int negI = -1;
  for (int t = 0; t < NTILE; ++t) {
    float4 p = *(const float4*)&cb[t * 8];
    int oI = __float_as_int(p.y);
    if (oI >= 0 && (posI < 0 || p.x > posD || (p.x == posD && oI < posI))) {
      posD = p.x; posI = oI; posC = p.z; posN = p.w;
    }
    float4 q = *(const float4*)&cb[t * 8 + 4];
    oI = __float_as_int(q.y);
    if (oI >= 0 && (negI < 0 || q.x < negD || (q.x == negD && oI < negI))) {
      negD = q.x; negI = oI; negC = q.z; negN = q.w;
    }
  }
  float snorm = sqrtf(s2arr[b * SS + s]);
  float sden = fmaxf(snorm, EPS_V);
  float pl = (posI >= 0) ? posC / (sden * fmaxf(sqrtf(posN), EPS_V)) : 0.f;
  float nl = (negI >= 0) ? negC / (sden * fmaxf(sqrtf(negN), EPS_V)) : 0.f;
  float v = pl + nl;
  for (int off = 32; off; off >>= 1) v += __shfl_down(v, off, 64);
  if (s == 0) gcn_b[b] = v;
}

// ---------------------------------------------------------------------------
// Kernel 5: final deterministic combine -> scalar.
// ---------------------------------------------------------------------------
__global__ void final_kernel(const float* __restrict__ loss01,
                             const float* __restrict__ actP,
                             const float* __restrict__ bkgP,
                             const float* __restrict__ gcn_b,
                             float* __restrict__ out) {
  float um = 0.f, g = 0.f;
  for (int b = 0; b < BB; ++b) {
    float na = 0.f, nb = 0.f;
    for (int k = 0; k < 8; ++k) { na += actP[b * 8 + k]; nb += bkgP[b * 8 + k]; }
    float la = fmaxf(MARGIN_W - sqrtf(na), 0.f);
    float lb = sqrtf(nb);
    um += (la + lb) * (la + lb);
    g += gcn_b[b];
  }
  um /= (float)BB;
  out[0] = loss01[0] + ALPHA_W * um + BETA_W * loss01[1] + GCN_W * g;
}

// ---------------------------------------------------------------------------
extern "C" void kernel_launch(void* const* d_in, const int* in_sizes, int n_in,
                              void* d_out, int out_size, void* d_ws,
                              size_t ws_size, hipStream_t stream) {
  const float* score_act = (const float*)d_in[0];
  const float* score_bkg = (const float*)d_in[1];
  const float* feat_act = (const float*)d_in[2];
  const float* feat_bkg = (const float*)d_in[3];
  const float* label = (const float*)d_in[4];
  // d_in[5] = gt, d_in[6] = cas: unused by the reference loss
  const float* nodes = (const float*)d_in[7];
  const int* nlab = (const int*)d_in[8];
  const int* sidx = (const int*)d_in[9];
  float* out = (float*)d_out;

  float* wsf = (float*)d_ws;
  float* loss01 = wsf;           // 2 floats
  float* gcn_b = wsf + 32;       // 32
  float* actP = wsf + 64;        // 256
  float* bkgP = wsf + 320;       // 256
  float* s2arr = wsf + 576;      // 2048
  float* cand = wsf + 4096;      // 32*64*12*8 = 196608 (16B-aligned offset)

  bce_kernel<<<1, 640, 0, stream>>>(score_act, score_bkg, label, loss01);
  feat_norm_kernel<<<dim3(8, BB), 256, 0, stream>>>(feat_act, actP);
  feat_norm_kernel<<<dim3(8, BB), 256, 0, stream>>>(feat_bkg, bkgP);
  gcn_tile_kernel<<<dim3(NTILE, BB), 256, 0, stream>>>(nodes, nlab, sidx, cand,
                                                       s2arr);
  gcn_combine_kernel<<<BB, SS, 0, stream>>>(cand, s2arr, gcn_b);
  final_kernel<<<1, 1, 0, stream>>>(loss01, actP, bkgP, gcn_b, out);
}

// Round 2
// 254.787 us; speedup vs baseline: 2.1024x; 2.1024x over previous
//
#include <hip/hip_runtime.h>
#include <math.h>

// Problem constants (from reference setup_inputs)
#define BB 32
#define TT 750
#define DD 2048
#define CC 20
#define MM 750
#define SS 64
#define MT 64          // gcn m-tile
#define NT 12          // ceil(750/64)
#define TSPLIT 8       // feat t-split
#define TCH 94         // ceil(750/8)

#define GCN_BLOCKS (NT * BB)            // 384
#define FEAT_BLOCKS (2 * BB * TSPLIT)   // 512

#define ALPHA_W 0.0005f
#define BETA_W 0.1f
#define MARGIN_W 100.0f
#define GCN_W 0.1f
#define EPS_V 1e-8f

// ws float offsets
#define WS_LOSS01 0
#define WS_N2ACT 16
#define WS_N2BKG 48
#define WS_GCNB 80
#define WS_S2 128          // 2048 floats
#define WS_CAND 4096       // 32*64*12*8 = 196608 floats
#define WS_COLSUM 200704   // 2*32*8*2048 = 1048576 floats

// XOR-swizzled LDS slot (units of float4). Row stride 16 f4 == 0 mod 8 bank
// groups, so the key must decorrelate rows: key = ((r>>2)^r)&7 gives each
// bank group exactly 2 lanes for both the stride-2 B reads and the staging
// writes (2-way on 32 banks is free).
__device__ __forceinline__ int slot4(int r, int c) {
  return r * 16 + (c ^ (((r >> 2) ^ r) & 7));
}

// ---------------------------------------------------------------------------
// Mega kernel: [0,384) gcn tiles | [384,896) feat colsums | 896 bce.
// Fusing overlaps the VALU/LDS-bound gcn work with the HBM-bound feat sweep.
// ---------------------------------------------------------------------------
__global__ __launch_bounds__(256, 3) void mega_kernel(
    const float* __restrict__ score_act, const float* __restrict__ score_bkg,
    const float* __restrict__ feat_act, const float* __restrict__ feat_bkg,
    const float* __restrict__ label, const float* __restrict__ nodes,
    const int* __restrict__ nlab, const int* __restrict__ sidx,
    float* __restrict__ ws) {
  int bx = blockIdx.x;
  int tid = threadIdx.x;

  if (bx < GCN_BLOCKS) {
    // ---------------- GCN tile: batch b, 64-m tile ----------------
    int b = bx / NT, tile = bx % NT;
    __shared__ __align__(16) float sA[SS * 64];
    __shared__ __align__(16) float sB[MT * 64];
    __shared__ float sS2[SS];
    __shared__ float sN2[MT];
    __shared__ int sSlab[SS];
    __shared__ int sMlab[MT];

    if (tid < SS) {
      sSlab[tid] = nlab[b * MM + sidx[b * SS + tid]];
    } else if (tid < SS + MT) {
      int ml = tid - SS;
      int m = tile * MT + ml;
      sMlab[ml] = (m < MM) ? nlab[b * MM + m] : -2;
    }

    // staging: thread loads rows r0+16k, f4-column d4 (A: s_nodes, B: nodes)
    int r0 = tid >> 4, d4 = tid & 15;
    const float* aptr[4];
    const float* bptr[4];
    bool bval[4];
    int wSlot[4];
#pragma unroll
    for (int k = 0; k < 4; ++k) {
      int row = r0 + 16 * k;
      aptr[k] = nodes + ((size_t)b * MM + sidx[b * SS + row]) * DD + d4 * 4;
      int m = tile * MT + row;
      bval[k] = (m < MM);
      bptr[k] = nodes + ((size_t)b * MM + (bval[k] ? m : 0)) * DD + d4 * 4;
      wSlot[k] = slot4(row, d4);
    }

    // compute mapping: 8s x 2m per thread; quarter-wave shares sg -> A reads
    // are 16-lane broadcasts (cheap), only 2 distinct B reads per f4-step.
    int sg = tid >> 5, mg = tid & 31;
    int aBase[8], aKey[8];
#pragma unroll
    for (int i = 0; i < 8; ++i) {
      int r = sg * 8 + i;
      aBase[i] = r * 16;
      aKey[i] = ((r >> 2) ^ r) & 7;
    }
    int bBase[2], bKey[2];
#pragma unroll
    for (int j = 0; j < 2; ++j) {
      int r = mg * 2 + j;
      bBase[j] = r * 16;
      bKey[j] = ((r >> 2) ^ r) & 7;
    }

    float aSq[4] = {0.f, 0.f, 0.f, 0.f};
    float bSq[4] = {0.f, 0.f, 0.f, 0.f};
    float acc[8][2];
#pragma unroll
    for (int i = 0; i < 8; ++i) {
      acc[i][0] = 0.f;
      acc[i][1] = 0.f;
    }

    float4* sA4 = (float4*)sA;
    float4* sB4 = (float4*)sB;

    for (int ch = 0; ch < DD / 64; ++ch) {
      int off = ch * 64;
      __syncthreads();  // protect previous iteration's LDS reads
#pragma unroll
      for (int k = 0; k < 4; ++k) {
        float4 v = *(const float4*)(aptr[k] + off);
        sA4[wSlot[k]] = v;
        aSq[k] += v.x * v.x + v.y * v.y + v.z * v.z + v.w * v.w;
        float4 w = bval[k] ? *(const float4*)(bptr[k] + off)
                           : make_float4(0.f, 0.f, 0.f, 0.f);
        sB4[wSlot[k]] = w;
        bSq[k] += w.x * w.x + w.y * w.y + w.z * w.z + w.w * w.w;
      }
      __syncthreads();
#pragma unroll 4
      for (int c = 0; c < 16; ++c) {
        float4 av[8], bv[2];
#pragma unroll
        for (int i = 0; i < 8; ++i) av[i] = sA4[aBase[i] + (c ^ aKey[i])];
#pragma unroll
        for (int j = 0; j < 2; ++j) bv[j] = sB4[bBase[j] + (c ^ bKey[j])];
#pragma unroll
        for (int i = 0; i < 8; ++i)
#pragma unroll
          for (int j = 0; j < 2; ++j)
            acc[i][j] += av[i].x * bv[j].x + av[i].y * bv[j].y +
                         av[i].z * bv[j].z + av[i].w * bv[j].w;
      }
    }

    // reduce per-row sums of squares across the 16 d4 lanes
#pragma unroll
    for (int k = 0; k < 4; ++k) {
      float va = aSq[k], vb = bSq[k];
      va += __shfl_down(va, 8, 16);
      va += __shfl_down(va, 4, 16);
      va += __shfl_down(va, 2, 16);
      va += __shfl_down(va, 1, 16);
      vb += __shfl_down(vb, 8, 16);
      vb += __shfl_down(vb, 4, 16);
      vb += __shfl_down(vb, 2, 16);
      vb += __shfl_down(vb, 1, 16);
      if (d4 == 0) {
        sS2[r0 + 16 * k] = va;
        sN2[r0 + 16 * k] = vb;
      }
    }
    __syncthreads();

    if (tile == 0 && tid < SS) ws[WS_S2 + b * SS + tid] = sS2[tid];

    // per-s masked argmax/argmin with JAX first-index tie-breaking
#pragma unroll
    for (int i = 0; i < 8; ++i) {
      int s = sg * 8 + i;
      int slab = sSlab[s];
      float s2v = sS2[s];
      float posD = -3.4e38f, posC = 0.f, posN = 0.f;
      int posI = -1;
      float negD = 3.4e38f, negC = 0.f, negN = 0.f;
      int negI = -1;
#pragma unroll
      for (int j = 0; j < 2; ++j) {
        int ml = mg * 2 + j;
        int m = tile * MT + ml;
        int lab = sMlab[ml];
        float cv = acc[i][j];
        float n2 = sN2[ml];
        float d2 = fmaxf(s2v + n2 - 2.f * cv, 0.f);
        bool valid = (lab >= 0);
        if (valid && lab == slab && (posI < 0 || d2 > posD)) {
          posD = d2; posI = m; posC = cv; posN = n2;
        }
        if (valid && lab != slab && (negI < 0 || d2 < negD)) {
          negD = d2; negI = m; negC = cv; negN = n2;
        }
      }
      // tuple reduce across the 32 mg lanes (sg groups == shfl width-32 halves)
#pragma unroll
      for (int off = 16; off; off >>= 1) {
        float oD = __shfl_down(posD, off, 32);
        int oI = __shfl_down(posI, off, 32);
        float oC = __shfl_down(posC, off, 32);
        float oN = __shfl_down(posN, off, 32);
        bool take = (oI >= 0) &&
                    (posI < 0 || oD > posD || (oD == posD && oI < posI));
        if (take) { posD = oD; posI = oI; posC = oC; posN = oN; }
        oD = __shfl_down(negD, off, 32);
        oI = __shfl_down(negI, off, 32);
        oC = __shfl_down(negC, off, 32);
        oN = __shfl_down(negN, off, 32);
        take = (oI >= 0) &&
               (negI < 0 || oD < negD || (oD == negD && oI < negI));
        if (take) { negD = oD; negI = oI; negC = oC; negN = oN; }
      }
      if (mg == 0) {
        size_t base = (((size_t)b * SS + s) * NT + tile) * 8;
        *(float4*)&ws[WS_CAND + base] =
            make_float4(posD, __int_as_float(posI), posC, posN);
        *(float4*)&ws[WS_CAND + base + 4] =
            make_float4(negD, __int_as_float(negI), negC, negN);
      }
    }
  } else if (bx < GCN_BLOCKS + FEAT_BLOCKS) {
    // ---------------- feat column-sum partials (HBM-bound) ----------------
    int idx = bx - GCN_BLOCKS;
    int tz = idx >> 8;   // 0: act, 1: bkg
    int rem = idx & 255;
    int fb = rem >> 3;   // batch
    int blk = rem & 7;   // t-chunk
    const float* feat = tz ? feat_bkg : feat_act;
    int t0 = blk * TCH;
    int t1 = t0 + TCH < TT ? t0 + TCH : TT;
    int d0 = tid * 4;
    float4 s0 = make_float4(0.f, 0.f, 0.f, 0.f);
    float4 s1 = make_float4(0.f, 0.f, 0.f, 0.f);
    const float* base = feat + (size_t)fb * TT * DD;
    for (int t = t0; t < t1; ++t) {
      const float* p = base + (size_t)t * DD;
      float4 v = *(const float4*)(p + d0);
      float4 w = *(const float4*)(p + d0 + 1024);
      s0.x += v.x; s0.y += v.y; s0.z += v.z; s0.w += v.w;
      s1.x += w.x; s1.y += w.y; s1.z += w.z; s1.w += w.w;
    }
    float* cs = ws + WS_COLSUM + ((size_t)(tz * BB + fb) * TSPLIT + blk) * DD;
    *(float4*)(cs + d0) = s0;
    *(float4*)(cs + d0 + 1024) = s1;
  } else {
    // ---------------- BCE losses ----------------
    float vc = 0.f, vb = 0.f;
    for (int i = tid; i < BB * CC; i += 256) {
      int b = i / CC, c = i % CC;
      float rs = 0.f;
      for (int k = 0; k < CC; ++k) rs += label[b * CC + k];
      float ln = label[b * CC + c] / rs;
      float pa = score_act[i];
      vc += ln * logf(pa) + (1.f - ln) * logf(1.f - pa);
      float pb = score_bkg[i];
      const float tb = 1.f / (float)CC;
      vb += tb * logf(pb) + (1.f - tb) * logf(1.f - pb);
    }
    for (int off = 32; off; off >>= 1) {
      vc += __shfl_down(vc, off, 64);
      vb += __shfl_down(vb, off, 64);
    }
    __shared__ float rc[4], rb[4];
    if ((tid & 63) == 0) {
      rc[tid >> 6] = vc;
      rb[tid >> 6] = vb;
    }
    __syncthreads();
    if (tid == 0) {
      ws[WS_LOSS01] = -(rc[0] + rc[1] + rc[2] + rc[3]) / (float)(BB * CC);
      ws[WS_LOSS01 + 1] = -(rb[0] + rb[1] + rb[2] + rb[3]) / (float)(BB * CC);
    }
  }
}

// ---------------------------------------------------------------------------
// Tail: [0,64) feat norm finalize | [64,96) gcn per-(b,s) combine.
// ---------------------------------------------------------------------------
__global__ __launch_bounds__(256) void tail_kernel(float* __restrict__ ws) {
  int bx = blockIdx.x, tid = threadIdx.x;
  if (bx < 64) {
    int tz = bx >> 5, fb = bx & 31;
    const float* cs = ws + WS_COLSUM + (size_t)(tz * BB + fb) * TSPLIT * DD;
    int d0 = tid * 8;
    float4 A0 = make_float4(0.f, 0.f, 0.f, 0.f);
    float4 A1 = make_float4(0.f, 0.f, 0.f, 0.f);
    for (int blk = 0; blk < TSPLIT; ++blk) {
      const float* p = cs + blk * DD + d0;
      float4 u = *(const float4*)p;
      float4 w = *(const float4*)(p + 4);
      A0.x += u.x; A0.y += u.y; A0.z += u.z; A0.w += u.w;
      A1.x += w.x; A1.y += w.y; A1.z += w.z; A1.w += w.w;
    }
    const float inv = 1.f / (float)TT;
    float m0 = A0.x * inv, m1 = A0.y * inv, m2 = A0.z * inv, m3 = A0.w * inv;
    float m4 = A1.x * inv, m5 = A1.y * inv, m6 = A1.z * inv, m7 = A1.w * inv;
    float v = m0 * m0 + m1 * m1 + m2 * m2 + m3 * m3 +
              m4 * m4 + m5 * m5 + m6 * m6 + m7 * m7;
    for (int off = 32; off; off >>= 1) v += __shfl_down(v, off, 64);
    __shared__ float red[4];
    if ((tid & 63) == 0) red[tid >> 6] = v;
    __syncthreads();
    if (tid == 0)
      ws[(tz ? WS_N2BKG : WS_N2ACT) + fb] = red[0] + red[1] + red[2] + red[3];
  } else {
    int b = bx - 64;
    if (tid < SS) {
      const float* cb = ws + WS_CAND + ((size_t)b * SS + tid) * NT * 8;
      float posD = -3.4e38f, posC = 0.f, posN = 0.f;
      int posI = -1;
      float negD = 3.4e38f, negC = 0.f, negN = 0.f;
      int negI = -1;
      for (int t = 0; t < NT; ++t) {
        float4 p = *(const float4*)&cb[t * 8];
        int oI = __float_as_int(p.y);
        if (oI >= 0 && (posI < 0 || p.x > posD || (p.x == posD && oI < posI))) {
          posD = p.x; posI = oI; posC = p.z; posN = p.w;
        }
        float4 q = *(const float4*)&cb[t * 8 + 4];
        oI = __float_as_int(q.y);
        if (oI >= 0 && (negI < 0 || q.x < negD || (q.x == negD && oI < negI))) {
          negD = q.x; negI = oI; negC = q.z; negN = q.w;
        }
      }
      float snorm = sqrtf(ws[WS_S2 + b * SS + tid]);
      float sden = fmaxf(snorm, EPS_V);
      float pl = (posI >= 0) ? posC / (sden * fmaxf(sqrtf(posN), EPS_V)) : 0.f;
      float nl = (negI >= 0) ? negC / (sden * fmaxf(sqrtf(negN), EPS_V)) : 0.f;
      float v = pl + nl;
      for (int off = 32; off; off >>= 1) v += __shfl_down(v, off, 64);
      if (tid == 0) ws[WS_GCNB + b] = v;
    }
  }
}

// ---------------------------------------------------------------------------
// Final deterministic scalar combine.
// ---------------------------------------------------------------------------
__global__ void final_kernel(const float* __restrict__ ws,
                             float* __restrict__ out) {
  int tid = threadIdx.x;  // 64 threads
  float um = 0.f, g = 0.f;
  if (tid < BB) {
    float la = fmaxf(MARGIN_W - sqrtf(ws[WS_N2ACT + tid]), 0.f);
    float lb = sqrtf(ws[WS_N2BKG + tid]);
    um = (la + lb) * (la + lb);
    g = ws[WS_GCNB + tid];
  }
  for (int off = 32; off; off >>= 1) {
    um += __shfl_down(um, off, 64);
    g += __shfl_down(g, off, 64);
  }
  if (tid == 0)
    out[0] = ws[WS_LOSS01] + BETA_W * ws[WS_LOSS01 + 1] +
             ALPHA_W * (um / (float)BB) + GCN_W * g;
}

// ---------------------------------------------------------------------------
extern "C" void kernel_launch(void* const* d_in, const int* in_sizes, int n_in,
                              void* d_out, int out_size, void* d_ws,
                              size_t ws_size, hipStream_t stream) {
  const float* score_act = (const float*)d_in[0];
  const float* score_bkg = (const float*)d_in[1];
  const float* feat_act = (const float*)d_in[2];
  const float* feat_bkg = (const float*)d_in[3];
  const float* label = (const float*)d_in[4];
  // d_in[5] = gt, d_in[6] = cas: unused by the reference loss
  const float* nodes = (const float*)d_in[7];
  const int* nlab = (const int*)d_in[8];
  const int* sidx = (const int*)d_in[9];
  float* out = (float*)d_out;
  float* wsf = (float*)d_ws;

  mega_kernel<<<GCN_BLOCKS + FEAT_BLOCKS + 1, 256, 0, stream>>>(
      score_act, score_bkg, feat_act, feat_bkg, label, nodes, nlab, sidx, wsf);
  tail_kernel<<<96, 256, 0, stream>>>(wsf);
  final_kernel<<<1, 64, 0, stream>>>(wsf, out);
}

// Round 3
// 131.319 us; speedup vs baseline: 4.0792x; 1.9402x over previous
//
#include <hip/hip_runtime.h>
#include <math.h>

// Problem constants (from reference setup_inputs)
#define BB 32
#define TT 750
#define DD 2048
#define CC 20
#define MM 750
#define SS 64
#define MT 64          // gcn m-tile
#define NT 12          // ceil(750/64)
#define TSPLIT 8       // feat t-split
#define TCH 94         // ceil(750/8)

#define GCN_BLOCKS (NT * BB)            // 384
#define FEAT_BLOCKS (2 * BB * TSPLIT)   // 512
#define TOT_BLOCKS (GCN_BLOCKS + FEAT_BLOCKS + 1)  // 897 = 7*128 + 1

#define ALPHA_W 0.0005f
#define BETA_W 0.1f
#define MARGIN_W 100.0f
#define GCN_W 0.1f
#define EPS_V 1e-8f

// ws float offsets
#define WS_LOSS01 0
#define WS_N2ACT 16
#define WS_N2BKG 48
#define WS_GCNB 80
#define WS_S2 128          // 2048 floats
#define WS_CAND 4096       // 32*64*12*8 = 196608 floats
#define WS_COLSUM 200704   // 2*32*8*2048 = 1048576 floats

typedef __attribute__((ext_vector_type(8))) short bf16x8;
typedef __attribute__((ext_vector_type(4))) float f32x4;

// f32 -> bf16 round-to-nearest-even
__device__ __forceinline__ unsigned short f2bf(float f) {
  unsigned int u = __float_as_uint(f);
  return (unsigned short)((u + 0x7FFFu + ((u >> 16) & 1u)) >> 16);
}

// ---------------------------------------------------------------------------
// Mega kernel. Role interleave: id%7 in {0,1,2} -> gcn (384), {3..6} -> feat
// (512), id==896 -> bce. Fine interleave mixes MFMA-bound gcn with HBM-bound
// feat on every CU/XCD.
// ---------------------------------------------------------------------------
__global__ __launch_bounds__(256, 3) void mega_kernel(
    const float* __restrict__ score_act, const float* __restrict__ score_bkg,
    const float* __restrict__ feat_act, const float* __restrict__ feat_bkg,
    const float* __restrict__ label, const float* __restrict__ nodes,
    const int* __restrict__ nlab, const int* __restrict__ sidx,
    float* __restrict__ ws) {
  int bx = blockIdx.x;
  int tid = threadIdx.x;
  int q7 = bx / 7, r7 = bx % 7;

  if (bx < TOT_BLOCKS - 1 && r7 < 3) {
    // ---------------- GCN tile: batch b, 64-m tile, bf16 MFMA ----------------
    int idx = q7 * 3 + r7;
    int b = idx / NT, tile = idx % NT;

    // LDS: bf16 tiles, 64 rows x 64 k each; rows = 128B = 8 16B-units,
    // XOR-swizzled by (row&7) on the 16B unit index.
    __shared__ __align__(16) unsigned short sAh[64 * 64];
    __shared__ __align__(16) unsigned short sBh[64 * 64];
    __shared__ float sS2[SS];
    __shared__ float sN2[MT];
    __shared__ int sSlab[SS];
    __shared__ int sMlab[MT];

    if (tid < SS) {
      sSlab[tid] = nlab[b * MM + sidx[b * SS + tid]];
    } else if (tid < SS + MT) {
      int ml = tid - SS;
      int m = tile * MT + ml;
      sMlab[ml] = (m < MM) ? nlab[b * MM + m] : -2;
    }

    // staging: thread -> row r = tid>>2 (both A-s-row and B-m-row), p = tid&3,
    // covering 8B-granules u = p+4j (j=0..3) of the 64-f32 chunk row.
    int r = tid >> 2, p = tid & 3;
    const float* aRow = nodes + ((size_t)b * MM + sidx[b * SS + r]) * DD;
    int mrow = tile * MT + r;
    bool bval = (mrow < MM);
    const float* bRow = nodes + ((size_t)b * MM + (bval ? mrow : 0)) * DD;

    int wslot[4];  // ushort index of the 8B granule in the swizzled row
#pragma unroll
    for (int j = 0; j < 4; ++j) {
      int u = p + 4 * j;
      wslot[j] = r * 64 + ((((u >> 1) ^ (r & 7)) << 1) + (u & 1)) * 4;
    }

    int lane = tid & 63, w = tid >> 6;
    int g = lane >> 4, c = lane & 15;

    float aSq = 0.f, bSq = 0.f;
    f32x4 acc[4];
#pragma unroll
    for (int f = 0; f < 4; ++f) acc[f] = (f32x4){0.f, 0.f, 0.f, 0.f};

    // prefetch chunk 0
    float4 pa[4], pb[4];
#pragma unroll
    for (int j = 0; j < 4; ++j) {
      int off = (p + 4 * j) * 4;
      pa[j] = *(const float4*)(aRow + off);
      pb[j] = *(const float4*)(bRow + off);
    }

    for (int ch = 0; ch < 32; ++ch) {
      __syncthreads();  // previous chunk's LDS reads done
#pragma unroll
      for (int j = 0; j < 4; ++j) {
        float4 v = pa[j];
        aSq += v.x * v.x + v.y * v.y + v.z * v.z + v.w * v.w;
        unsigned int lo = (unsigned int)f2bf(v.x) | ((unsigned int)f2bf(v.y) << 16);
        unsigned int hi = (unsigned int)f2bf(v.z) | ((unsigned int)f2bf(v.w) << 16);
        *(uint2*)&sAh[wslot[j]] = make_uint2(lo, hi);
        float4 t = pb[j];
        bSq += t.x * t.x + t.y * t.y + t.z * t.z + t.w * t.w;
        lo = (unsigned int)f2bf(t.x) | ((unsigned int)f2bf(t.y) << 16);
        hi = (unsigned int)f2bf(t.z) | ((unsigned int)f2bf(t.w) << 16);
        *(uint2*)&sBh[wslot[j]] = make_uint2(lo, hi);
      }
      __syncthreads();  // tile visible
      if (ch < 31) {    // issue next chunk's loads; latency hides under MFMA
        const float* ap = aRow + (ch + 1) * 64;
        const float* bp = bRow + (ch + 1) * 64;
#pragma unroll
        for (int j = 0; j < 4; ++j) {
          int off = (p + 4 * j) * 4;
          pa[j] = *(const float4*)(ap + off);
          pb[j] = *(const float4*)(bp + off);
        }
      }
      // compute: 2 k-steps of 32 over the 64-k chunk
#pragma unroll
      for (int kk = 0; kk < 2; ++kk) {
        int su = kk * 4 + g;
        int arow = w * 16 + c;
        bf16x8 af = *(const bf16x8*)&sAh[arow * 64 + (su ^ (arow & 7)) * 8];
#pragma unroll
        for (int f = 0; f < 4; ++f) {
          int brow = f * 16 + c;
          bf16x8 bfr = *(const bf16x8*)&sBh[brow * 64 + (su ^ (brow & 7)) * 8];
          acc[f] = __builtin_amdgcn_mfma_f32_16x16x32_bf16(af, bfr, acc[f], 0, 0, 0);
        }
      }
    }

    // exact-f32 row sums of squares: reduce across the 4 p-lanes per row
    aSq += __shfl_down(aSq, 2, 4);
    aSq += __shfl_down(aSq, 1, 4);
    bSq += __shfl_down(bSq, 2, 4);
    bSq += __shfl_down(bSq, 1, 4);
    if (p == 0) {
      sS2[r] = aSq;
      sN2[r] = bSq;
    }
    __syncthreads();

    if (tile == 0 && tid < SS) ws[WS_S2 + b * SS + tid] = sS2[tid];

    // selection: lane holds C[s][m] for s = w*16+g*4+reg, m_local = f*16+c
#pragma unroll
    for (int reg = 0; reg < 4; ++reg) {
      int s = w * 16 + g * 4 + reg;
      int slab = sSlab[s];
      float s2v = sS2[s];
      float posD = -3.4e38f, posC = 0.f, posN = 0.f;
      int posI = -1;
      float negD = 3.4e38f, negC = 0.f, negN = 0.f;
      int negI = -1;
#pragma unroll
      for (int f = 0; f < 4; ++f) {
        int ml = f * 16 + c;
        int lab = sMlab[ml];
        float cv = acc[f][reg];
        float n2 = sN2[ml];
        float d2 = fmaxf(s2v + n2 - 2.f * cv, 0.f);
        if (lab >= 0 && lab == slab && (posI < 0 || d2 > posD)) {
          posD = d2; posI = tile * MT + ml; posC = cv; posN = n2;
        }
        if (lab >= 0 && lab != slab && (negI < 0 || d2 < negD)) {
          negD = d2; negI = tile * MT + ml; negC = cv; negN = n2;
        }
      }
      // tuple reduce across the 16 c-lanes (quarter-wave), JAX tie-break
#pragma unroll
      for (int off = 8; off; off >>= 1) {
        float oD = __shfl_down(posD, off, 16);
        int oI = __shfl_down(posI, off, 16);
        float oC = __shfl_down(posC, off, 16);
        float oN = __shfl_down(posN, off, 16);
        bool take = (oI >= 0) &&
                    (posI < 0 || oD > posD || (oD == posD && oI < posI));
        if (take) { posD = oD; posI = oI; posC = oC; posN = oN; }
        oD = __shfl_down(negD, off, 16);
        oI = __shfl_down(negI, off, 16);
        oC = __shfl_down(negC, off, 16);
        oN = __shfl_down(negN, off, 16);
        take = (oI >= 0) &&
               (negI < 0 || oD < negD || (oD == negD && oI < negI));
        if (take) { negD = oD; negI = oI; negC = oC; negN = oN; }
      }
      if (c == 0) {
        size_t base = (((size_t)b * SS + s) * NT + tile) * 8;
        *(float4*)&ws[WS_CAND + base] =
            make_float4(posD, __int_as_float(posI), posC, posN);
        *(float4*)&ws[WS_CAND + base + 4] =
            make_float4(negD, __int_as_float(negI), negC, negN);
      }
    }
  } else if (bx < TOT_BLOCKS - 1) {
    // ---------------- feat column-sum partials (HBM-bound) ----------------
    int idx = q7 * 4 + (r7 - 3);
    int tz = idx >> 8;   // 0: act, 1: bkg
    int rem = idx & 255;
    int fb = rem >> 3;   // batch
    int blk = rem & 7;   // t-chunk
    const float* feat = tz ? feat_bkg : feat_act;
    int t0 = blk * TCH;
    int t1 = t0 + TCH < TT ? t0 + TCH : TT;
    int d0 = tid * 4;
    float4 s0 = make_float4(0.f, 0.f, 0.f, 0.f);
    float4 s1 = make_float4(0.f, 0.f, 0.f, 0.f);
    const float* base = feat + (size_t)fb * TT * DD;
    for (int t = t0; t < t1; ++t) {
      const float* pp = base + (size_t)t * DD;
      float4 v = *(const float4*)(pp + d0);
      float4 u = *(const float4*)(pp + d0 + 1024);
      s0.x += v.x; s0.y += v.y; s0.z += v.z; s0.w += v.w;
      s1.x += u.x; s1.y += u.y; s1.z += u.z; s1.w += u.w;
    }
    float* cs = ws + WS_COLSUM + ((size_t)(tz * BB + fb) * TSPLIT + blk) * DD;
    *(float4*)(cs + d0) = s0;
    *(float4*)(cs + d0 + 1024) = s1;
  } else {
    // ---------------- BCE losses ----------------
    float vc = 0.f, vb = 0.f;
    for (int i = tid; i < BB * CC; i += 256) {
      int b = i / CC, c = i % CC;
      float rs = 0.f;
      for (int k = 0; k < CC; ++k) rs += label[b * CC + k];
      float ln = label[b * CC + c] / rs;
      float pa = score_act[i];
      vc += ln * logf(pa) + (1.f - ln) * logf(1.f - pa);
      float pb = score_bkg[i];
      const float tb = 1.f / (float)CC;
      vb += tb * logf(pb) + (1.f - tb) * logf(1.f - pb);
    }
    for (int off = 32; off; off >>= 1) {
      vc += __shfl_down(vc, off, 64);
      vb += __shfl_down(vb, off, 64);
    }
    __shared__ float rc[4], rb[4];
    if ((tid & 63) == 0) {
      rc[tid >> 6] = vc;
      rb[tid >> 6] = vb;
    }
    __syncthreads();
    if (tid == 0) {
      ws[WS_LOSS01] = -(rc[0] + rc[1] + rc[2] + rc[3]) / (float)(BB * CC);
      ws[WS_LOSS01 + 1] = -(rb[0] + rb[1] + rb[2] + rb[3]) / (float)(BB * CC);
    }
  }
}

// ---------------------------------------------------------------------------
// Tail: [0,64) feat norm finalize | [64,96) gcn per-(b,s) combine.
// ---------------------------------------------------------------------------
__global__ __launch_bounds__(256) void tail_kernel(float* __restrict__ ws) {
  int bx = blockIdx.x, tid = threadIdx.x;
  if (bx < 64) {
    int tz = bx >> 5, fb = bx & 31;
    const float* cs = ws + WS_COLSUM + (size_t)(tz * BB + fb) * TSPLIT * DD;
    int d0 = tid * 8;
    float4 A0 = make_float4(0.f, 0.f, 0.f, 0.f);
    float4 A1 = make_float4(0.f, 0.f, 0.f, 0.f);
    for (int blk = 0; blk < TSPLIT; ++blk) {
      const float* pp = cs + blk * DD + d0;
      float4 u = *(const float4*)pp;
      float4 v = *(const float4*)(pp + 4);
      A0.x += u.x; A0.y += u.y; A0.z += u.z; A0.w += u.w;
      A1.x += v.x; A1.y += v.y; A1.z += v.z; A1.w += v.w;
    }
    const float inv = 1.f / (float)TT;
    float m0 = A0.x * inv, m1 = A0.y * inv, m2 = A0.z * inv, m3 = A0.w * inv;
    float m4 = A1.x * inv, m5 = A1.y * inv, m6 = A1.z * inv, m7 = A1.w * inv;
    float v = m0 * m0 + m1 * m1 + m2 * m2 + m3 * m3 +
              m4 * m4 + m5 * m5 + m6 * m6 + m7 * m7;
    for (int off = 32; off; off >>= 1) v += __shfl_down(v, off, 64);
    __shared__ float red[4];
    if ((tid & 63) == 0) red[tid >> 6] = v;
    __syncthreads();
    if (tid == 0)
      ws[(tz ? WS_N2BKG : WS_N2ACT) + fb] = red[0] + red[1] + red[2] + red[3];
  } else {
    int b = bx - 64;
    if (tid < SS) {
      const float* cb = ws + WS_CAND + ((size_t)b * SS + tid) * NT * 8;
      float posD = -3.4e38f, posC = 0.f, posN = 0.f;
      int posI = -1;
      float negD = 3.4e38f, negC = 0.f, negN = 0.f;
      int negI = -1;
      for (int t = 0; t < NT; ++t) {
        float4 pq = *(const float4*)&cb[t * 8];
        int oI = __float_as_int(pq.y);
        if (oI >= 0 && (posI < 0 || pq.x > posD || (pq.x == posD && oI < posI))) {
          posD = pq.x; posI = oI; posC = pq.z; posN = pq.w;
        }
        float4 qq = *(const float4*)&cb[t * 8 + 4];
        oI = __float_as_int(qq.y);
        if (oI >= 0 && (negI < 0 || qq.x < negD || (qq.x == negD && oI < negI))) {
          negD = qq.x; negI = oI; negC = qq.z; negN = qq.w;
        }
      }
      float snorm = sqrtf(ws[WS_S2 + b * SS + tid]);
      float sden = fmaxf(snorm, EPS_V);
      float pl = (posI >= 0) ? posC / (sden * fmaxf(sqrtf(posN), EPS_V)) : 0.f;
      float nl = (negI >= 0) ? negC / (sden * fmaxf(sqrtf(negN), EPS_V)) : 0.f;
      float v = pl + nl;
      for (int off = 32; off; off >>= 1) v += __shfl_down(v, off, 64);
      if (tid == 0) ws[WS_GCNB + b] = v;
    }
  }
}

// ---------------------------------------------------------------------------
// Final deterministic scalar combine.
// ---------------------------------------------------------------------------
__global__ void final_kernel(const float* __restrict__ ws,
                             float* __restrict__ out) {
  int tid = threadIdx.x;  // 64 threads
  float um = 0.f, g = 0.f;
  if (tid < BB) {
    float la = fmaxf(MARGIN_W - sqrtf(ws[WS_N2ACT + tid]), 0.f);
    float lb = sqrtf(ws[WS_N2BKG + tid]);
    um = (la + lb) * (la + lb);
    g = ws[WS_GCNB + tid];
  }
  for (int off = 32; off; off >>= 1) {
    um += __shfl_down(um, off, 64);
    g += __shfl_down(g, off, 64);
  }
  if (tid == 0)
    out[0] = ws[WS_LOSS01] + BETA_W * ws[WS_LOSS01 + 1] +
             ALPHA_W * (um / (float)BB) + GCN_W * g;
}

// ---------------------------------------------------------------------------
extern "C" void kernel_launch(void* const* d_in, const int* in_sizes, int n_in,
                              void* d_out, int out_size, void* d_ws,
                              size_t ws_size, hipStream_t stream) {
  const float* score_act = (const float*)d_in[0];
  const float* score_bkg = (const float*)d_in[1];
  const float* feat_act = (const float*)d_in[2];
  const float* feat_bkg = (const float*)d_in[3];
  const float* label = (const float*)d_in[4];
  // d_in[5] = gt, d_in[6] = cas: unused by the reference loss
  const float* nodes = (const float*)d_in[7];
  const int* nlab = (const int*)d_in[8];
  const int* sidx = (const int*)d_in[9];
  float* out = (float*)d_out;
  float* wsf = (float*)d_ws;

  mega_kernel<<<TOT_BLOCKS, 256, 0, stream>>>(
      score_act, score_bkg, feat_act, feat_bkg, label, nodes, nlab, sidx, wsf);
  tail_kernel<<<96, 256, 0, stream>>>(wsf);
  final_kernel<<<1, 64, 0, stream>>>(wsf, out);
}